// Round 2
// baseline (4845.612 us; speedup 1.0000x reference)
//
#include <hip/hip_runtime.h>
#include <cmath>

// ---------------------------------------------------------------------------
// LSTM T=512 B=64 I=512 H=512, fp32 in/out, bf16 MFMA compute.
// Phase A: Xg[t][g][b][h] = X@Wx_g + b_g   (bf16 MFMA GEMM, 128x128 tile)
// Phase B: persistent 32-block scan. Self-tagged h words (tag|bf16), relaxed
//          agent atomics, parity double-buffer. Full-K per wave, weights in
//          registers, one __syncthreads per step, no cross-wave reduce.
// ---------------------------------------------------------------------------

typedef __attribute__((ext_vector_type(8)))  short   short8;
typedef __attribute__((ext_vector_type(4)))  short   short4v;
typedef __attribute__((ext_vector_type(4)))  float   f32x4;
typedef __attribute__((ext_vector_type(16))) float   f32x16;

#define TSTEPS 512

__device__ __forceinline__ unsigned short f2bf(float f) {
  unsigned u = __builtin_bit_cast(unsigned, f);
  unsigned r = (u + 0x7FFFu + ((u >> 16) & 1u)) >> 16;
  return (unsigned short)r;
}
__device__ __forceinline__ float bf2f(unsigned short s) {
  unsigned u = ((unsigned)s) << 16;
  return __builtin_bit_cast(float, u);
}
__device__ __forceinline__ void gload_lds16(const void* g, void* l) {
  __builtin_amdgcn_global_load_lds(
      (const __attribute__((address_space(1))) unsigned int*)g,
      (__attribute__((address_space(3))) unsigned int*)l, 16, 0, 0);
}
__device__ __forceinline__ float sigmoidf_(float x) {
  return 1.0f / (1.0f + __expf(-x));
}

// ---------------------------------------------------------------------------
// Prep: transpose+convert the 8 weight matrices [512][512] f32 (k-major)
// into WxT / WhT bf16 [g*512+h][k] (n-major).
// ---------------------------------------------------------------------------
__global__ __launch_bounds__(256) void prep_wT(
    const float* __restrict__ Wax, const float* __restrict__ Wix,
    const float* __restrict__ Wfx, const float* __restrict__ Wox,
    const float* __restrict__ Wah, const float* __restrict__ Wih,
    const float* __restrict__ Wfh, const float* __restrict__ Woh,
    unsigned short* __restrict__ WxT, unsigned short* __restrict__ WhT) {
  __shared__ float tile[32][33];
  int bx = blockIdx.x;              // 8 mats * 256 tiles
  int mat = bx >> 8;
  int t32 = bx & 255;
  int k0 = (t32 & 15) * 32;
  int h0 = (t32 >> 4) * 32;
  const float* S =
      (mat == 0) ? Wax : (mat == 1) ? Wix : (mat == 2) ? Wfx :
      (mat == 3) ? Wox : (mat == 4) ? Wah : (mat == 5) ? Wih :
      (mat == 6) ? Wfh : Woh;
  unsigned short* D = (mat < 4) ? WxT : WhT;
  int g = mat & 3;
  int tx = threadIdx.x & 31, ty = threadIdx.x >> 5;  // ty in [0,8)
#pragma unroll
  for (int r = 0; r < 4; ++r)
    tile[ty + r * 8][tx] = S[(size_t)(k0 + ty + r * 8) * 512 + h0 + tx];
  __syncthreads();
#pragma unroll
  for (int r = 0; r < 4; ++r) {
    int h = h0 + ty + r * 8;
    int k = k0 + tx;
    D[((size_t)(g * 512 + h) << 9) + k] = f2bf(tile[tx][ty + r * 8]);
  }
}

// X f32 [32768][512] -> bf16
__global__ __launch_bounds__(256) void prep_xbf(const float* __restrict__ X,
                                                unsigned short* __restrict__ Xbf) {
  size_t i = (size_t)blockIdx.x * 256 + threadIdx.x;
  f32x4 v = *(const f32x4*)(X + i * 4);
  short4v o;
  o[0] = (short)f2bf(v[0]); o[1] = (short)f2bf(v[1]);
  o[2] = (short)f2bf(v[2]); o[3] = (short)f2bf(v[3]);
  *(short4v*)(Xbf + i * 4) = o;
}

__global__ __launch_bounds__(256) void prep_bias(
    const float* __restrict__ ba, const float* __restrict__ bi,
    const float* __restrict__ bf, const float* __restrict__ bo,
    float* __restrict__ biascat) {
  int n = blockIdx.x * 256 + threadIdx.x;  // [0,2048)
  int g = n >> 9, h = n & 511;
  const float* s = (g == 0) ? ba : (g == 1) ? bi : (g == 2) ? bf : bo;
  biascat[n] = s[h];
}

// ---------------------------------------------------------------------------
// Phase A: Xg(bf16)[t][g][b][h] = Xbf @ WxT^T + bias. (unchanged, ~100us)
// ---------------------------------------------------------------------------
__global__ __launch_bounds__(256) void gemm_xproj(
    const unsigned short* __restrict__ Xbf,   // [32768][512]
    const unsigned short* __restrict__ WxT,   // [2048][512]
    const float* __restrict__ biascat,        // [2048]
    unsigned short* __restrict__ Xg) {        // [512][4][64][512] bf16
  __shared__ unsigned short Asm[128 * 64];
  __shared__ unsigned short Bsm[128 * 64];
  int bx = blockIdx.x;
  int nt = bx & 15, mt = bx >> 4;
  int m0 = mt * 128, n0 = nt * 128;
  int tid = threadIdx.x;
  int w = tid >> 6, l = tid & 63;
  int wm = (w >> 1) * 64, wn = (w & 1) * 64;
  f32x4 acc[4][4] = {};

  for (int ks = 0; ks < 8; ++ks) {
    int k0 = ks * 64;
    __syncthreads();
    int lr = l >> 3;
    int ksl = ((l & 7) ^ lr) * 8;
#pragma unroll
    for (int ii = 0; ii < 4; ++ii) {
      int i = w * 4 + ii;
      int r = i * 8 + lr;
      gload_lds16(Xbf + (size_t)(m0 + r) * 512 + k0 + ksl, Asm + i * 512 + l * 8);
    }
#pragma unroll
    for (int ii = 0; ii < 4; ++ii) {
      int i = w * 4 + ii;
      int r = i * 8 + lr;
      gload_lds16(WxT + (size_t)(n0 + r) * 512 + k0 + ksl, Bsm + i * 512 + l * 8);
    }
    __syncthreads();
#pragma unroll
    for (int kk = 0; kk < 2; ++kk) {
      short8 af[4], bfr[4];
#pragma unroll
      for (int mi = 0; mi < 4; ++mi) {
        int row = wm + mi * 16 + (l & 15);
        int slot = (kk * 4 + (l >> 4)) ^ (row & 7);
        af[mi] = *(const short8*)(Asm + row * 64 + slot * 8);
      }
#pragma unroll
      for (int ni = 0; ni < 4; ++ni) {
        int row = wn + ni * 16 + (l & 15);
        int slot = (kk * 4 + (l >> 4)) ^ (row & 7);
        bfr[ni] = *(const short8*)(Bsm + row * 64 + slot * 8);
      }
#pragma unroll
      for (int mi = 0; mi < 4; ++mi)
#pragma unroll
        for (int ni = 0; ni < 4; ++ni)
          acc[mi][ni] = __builtin_amdgcn_mfma_f32_16x16x32_bf16(
              af[mi], bfr[ni], acc[mi][ni], 0, 0, 0);
    }
  }
#pragma unroll
  for (int mi = 0; mi < 4; ++mi)
#pragma unroll
    for (int ni = 0; ni < 4; ++ni) {
      int col = n0 + wn + ni * 16 + (l & 15);
      float bias = biascat[col];
      int g = col >> 9, h = col & 511;
#pragma unroll
      for (int r = 0; r < 4; ++r) {
        int m = m0 + wm + mi * 16 + (l >> 4) * 4 + r;
        int t = m >> 6, b = m & 63;
        Xg[(((size_t)(t * 4 + g) * 64 + b) << 9) + h] =
            f2bf(acc[mi][ni][r] + bias);
      }
    }
}

// ---------------------------------------------------------------------------
// Phase B: persistent scan, v2.
// 32 blocks x 4 waves. Block j: batch group mi=j&1 (rows mi*32..+31),
// col chunk cc=j>>1 (hcols cc*32..+31, all 4 gates). Wave w owns 8 hcols
// (4 gates x 8 = 32 MFMA cols), full K=512: 32x mfma_32x32x16, weights in
// 128 VGPRs. h handoff: tagged u32 words ((t+1)<<16 | bf16), relaxed-agent
// atomics, parity double buffer. One __syncthreads per step.
// ---------------------------------------------------------------------------
__global__ __launch_bounds__(256, 1) void lstm_scan(
    const unsigned short* __restrict__ Xg,   // [512][4][64][512] bf16
    const unsigned short* __restrict__ WhT,  // [2048][512] bf16
    unsigned* __restrict__ hbuf,             // [2][64][512] tagged u32 (zeroed)
    float* __restrict__ out) {               // [512][64][512] f32
  __shared__ unsigned short hsm[2][32 * 512];  // staged h (bf16), parity dbuf
  __shared__ float red[4][32 * 33];            // per-wave transpose scratch

  const int j = blockIdx.x;   // 0..31
  const int mi = j & 1;
  const int cc = j >> 1;
  const int tid = threadIdx.x;
  const int w = tid >> 6, l = tid & 63;

  // ---- recurrent weight fragments: resident in registers all 512 steps ----
  // B-frag (32x32x16): col=l&31 -> gate g=c>>3, hcol local c&7; k=(l>>5)*8+i
  short8 wf[32];
  {
    const int c = l & 31;
    const int g = c >> 3;
    const int hcol_w = cc * 32 + w * 8 + (c & 7);
    const unsigned short* base =
        WhT + (((size_t)(g * 512 + hcol_w)) << 9) + (l >> 5) * 8;
#pragma unroll
    for (int kt = 0; kt < 32; ++kt) wf[kt] = *(const short8*)(base + kt * 16);
  }

  // ---- staging map: thread -> row (tid>>3), k slices (tid&7)*4 + i*32 ----
  const int srow = tid >> 3;
  const int sk0 = (tid & 7) * 4;
  const int hrow_glob = mi * 32 + srow;

  // ---- elementwise map: lane -> 1 batch row, 4 consecutive hcols ----
  const int b_loc = l >> 1;
  const int b_glob = mi * 32 + b_loc;
  const int hcol = cc * 32 + w * 8 + (l & 1) * 4;

  float s4[4] = {0.f, 0.f, 0.f, 0.f};  // cell state, registers, all steps

#pragma unroll 1
  for (int t = 0; t < TSTEPS; ++t) {
    // ---- Xg prefetch (issued before poll; hides under the wait) ----
    float xg[4][4];
#pragma unroll
    for (int g = 0; g < 4; ++g) {
      const unsigned short* xp =
          Xg + (((size_t)((t * 4 + g) * 64 + b_glob)) << 9) + hcol;
      uint2 u = *(const uint2*)xp;
      xg[g][0] = bf2f((unsigned short)(u.x & 0xFFFFu));
      xg[g][1] = bf2f((unsigned short)(u.x >> 16));
      xg[g][2] = bf2f((unsigned short)(u.y & 0xFFFFu));
      xg[g][3] = bf2f((unsigned short)(u.y >> 16));
    }

    f32x16 acc = {};
    if (t > 0) {
      // ---- poll tagged h(t-1): every word self-validates (tag == t) ----
      const unsigned want = ((unsigned)t) << 16;
      const unsigned* hb =
          hbuf + ((size_t)((t - 1) & 1)) * 32768 + (hrow_glob << 9) + sk0;
      unsigned v[64];
      int pass;
      do {
#pragma unroll
        for (int i = 0; i < 16; ++i)
#pragma unroll
          for (int q = 0; q < 4; ++q)
            v[i * 4 + q] = __hip_atomic_load(hb + i * 32 + q, __ATOMIC_RELAXED,
                                             __HIP_MEMORY_SCOPE_AGENT);
        unsigned d = 0;
#pragma unroll
        for (int i = 0; i < 64; ++i) d |= (v[i] ^ want);
        pass = ((d & 0xFFFF0000u) == 0u);
        if (!pass) __builtin_amdgcn_s_sleep(1);
      } while (!pass);
      // ---- pack bf16 and stage into LDS (xor-swizzled rows) ----
      unsigned short* hs = hsm[t & 1];
#pragma unroll
      for (int i = 0; i < 16; ++i) {
        unsigned p0 = __builtin_amdgcn_perm(v[i * 4 + 1], v[i * 4 + 0], 0x05040100u);
        unsigned p1 = __builtin_amdgcn_perm(v[i * 4 + 3], v[i * 4 + 2], 0x05040100u);
        int idx = srow * 512 + sk0 + i * 32;
        int sw = idx ^ ((srow & 7) << 3);
        uint2 pk; pk.x = p0; pk.y = p1;
        *(uint2*)(hs + sw) = pk;
      }
      __syncthreads();  // the only barrier per step
      // ---- 32 MFMAs over full K=512 ----
      const unsigned short* hr = hsm[t & 1];
      const int arow = l & 31;
      const int abase = arow * 512 + (l >> 5) * 8;
      const int axor = (arow & 7) << 3;
#pragma unroll
      for (int kt = 0; kt < 32; ++kt) {
        short8 a = *(const short8*)(hr + ((abase + kt * 16) ^ axor));
        acc = __builtin_amdgcn_mfma_f32_32x32x16_bf16(a, wf[kt], acc, 0, 0, 0);
      }
    }
    // ---- wave-local transpose: C/D col=l&31, row=(r&3)+8*(r>>2)+4*(l>>5) ----
    {
      const int col = l & 31;
      float* rw = red[w];
#pragma unroll
      for (int r = 0; r < 16; ++r) {
        int row = (r & 3) + 8 * (r >> 2) + 4 * (l >> 5);
        rw[row * 33 + col] = acc[r];
      }
    }
    asm volatile("s_waitcnt lgkmcnt(0)" ::: "memory");
    __builtin_amdgcn_sched_barrier(0);
    float hout[4];
    {
      const float* rw = red[w];
#pragma unroll
      for (int q = 0; q < 4; ++q) {
        float pre[4];
#pragma unroll
        for (int g = 0; g < 4; ++g)
          pre[g] = rw[b_loc * 33 + g * 8 + (l & 1) * 4 + q] + xg[g][q];
        float a = tanhf(pre[0]);
        float ig = sigmoidf_(pre[1]);
        float fg = sigmoidf_(pre[2]);
        float og = sigmoidf_(pre[3]);
        s4[q] = a * ig + s4[q] * fg;
        hout[q] = tanhf(s4[q]) * og;
      }
    }
    // ---- stores: out (plain f32x4), h (4 tagged agent-scope words) ----
    f32x4 ov;
    ov[0] = hout[0]; ov[1] = hout[1]; ov[2] = hout[2]; ov[3] = hout[3];
    *(f32x4*)(out + ((size_t)t * 64 + b_glob) * 512 + hcol) = ov;
    const unsigned tag = ((unsigned)(t + 1)) << 16;
    unsigned* hw = hbuf + ((size_t)(t & 1)) * 32768 + (b_glob << 9) + hcol;
#pragma unroll
    for (int q = 0; q < 4; ++q)
      __hip_atomic_store(hw + q, tag | (unsigned)f2bf(hout[q]),
                         __ATOMIC_RELAXED, __HIP_MEMORY_SCOPE_AGENT);
  }
}

// ---------------------------------------------------------------------------
// Workspace layout (bytes):
//   0          Xg bf16     134217728
//   134217728  Xbf bf16     33554432   (dead after gemm_xproj; hbuf overlaps)
//   134217728  hbuf u32       262144   (memset AFTER gemm_xproj)
//   167772160  WxT bf16      2097152
//   169869312  WhT bf16      2097152
//   171966464  biascat f32      8192
// ---------------------------------------------------------------------------
extern "C" void kernel_launch(void* const* d_in, const int* in_sizes, int n_in,
                              void* d_out, int out_size, void* d_ws,
                              size_t ws_size, hipStream_t stream) {
  const float* X   = (const float*)d_in[0];
  const float* Wax = (const float*)d_in[1];
  const float* Wix = (const float*)d_in[2];
  const float* Wfx = (const float*)d_in[3];
  const float* Wox = (const float*)d_in[4];
  const float* Wah = (const float*)d_in[5];
  const float* Wih = (const float*)d_in[6];
  const float* Wfh = (const float*)d_in[7];
  const float* Woh = (const float*)d_in[8];
  const float* ba  = (const float*)d_in[9];
  const float* bi  = (const float*)d_in[10];
  const float* bf  = (const float*)d_in[11];
  const float* bo  = (const float*)d_in[12];

  char* ws = (char*)d_ws;
  unsigned short* Xg   = (unsigned short*)(ws);
  unsigned short* Xbf  = (unsigned short*)(ws + 134217728);
  unsigned*       hbuf = (unsigned*)(ws + 134217728);  // reuses Xbf space
  unsigned short* WxT  = (unsigned short*)(ws + 167772160);
  unsigned short* WhT  = (unsigned short*)(ws + 169869312);
  float*          bcat = (float*)(ws + 171966464);

  prep_wT<<<2048, 256, 0, stream>>>(Wax, Wix, Wfx, Wox, Wah, Wih, Wfh, Woh,
                                    WxT, WhT);
  prep_xbf<<<16384, 256, 0, stream>>>(X, Xbf);
  prep_bias<<<8, 256, 0, stream>>>(ba, bi, bf, bo, bcat);
  gemm_xproj<<<4096, 256, 0, stream>>>(Xbf, WxT, bcat, Xg);
  // hbuf overlaps Xbf: zero it only after gemm_xproj consumed Xbf
  hipMemsetAsync(ws + 134217728, 0, 262144, stream);
  lstm_scan<<<32, 256, 0, stream>>>(Xg, WhT, hbuf, (float*)d_out);
}

// Round 3
// 2641.661 us; speedup vs baseline: 1.8343x; 1.8343x over previous
//
#include <hip/hip_runtime.h>
#include <cmath>

// ---------------------------------------------------------------------------
// LSTM T=512 B=64 I=512 H=512, fp32 in/out, bf16 MFMA compute.
// Phase A: Xg = X@Wx + b  (bf16 MFMA GEMM), output re-laid as [t4g][chunk][b][8]
// Phase B: persistent 32-block scan, wave-autonomous (no LDS, no barriers):
//   - operand-swapped MFMA (A=WhT, B=h) -> gates lane-local, no transpose
//   - coalesced sc0sc1 (L2-bypass) h stores/loads, per-wave flags
//   - out stores + Xg prefetch off the critical path
// ---------------------------------------------------------------------------

typedef __attribute__((ext_vector_type(8)))  short   short8;
typedef __attribute__((ext_vector_type(4)))  short   short4v;
typedef __attribute__((ext_vector_type(4)))  float   f32x4;
typedef __attribute__((ext_vector_type(16))) float   f32x16;

#define TSTEPS 512

__device__ __forceinline__ unsigned short f2bf(float f) {
  unsigned u = __builtin_bit_cast(unsigned, f);
  unsigned r = (u + 0x7FFFu + ((u >> 16) & 1u)) >> 16;
  return (unsigned short)r;
}
__device__ __forceinline__ float bf2f(unsigned short s) {
  unsigned u = ((unsigned)s) << 16;
  return __builtin_bit_cast(float, u);
}
__device__ __forceinline__ void gload_lds16(const void* g, void* l) {
  __builtin_amdgcn_global_load_lds(
      (const __attribute__((address_space(1))) unsigned int*)g,
      (__attribute__((address_space(3))) unsigned int*)l, 16, 0, 0);
}
__device__ __forceinline__ float sigmoid_fast(float x) {
  return 1.0f / (1.0f + __expf(-x));
}
__device__ __forceinline__ float tanh_fast(float x) {
  // 1 - 2/(e^{2x}+1): x>>0 -> e=inf -> 1; x<<0 -> e=0 -> -1. No NaN.
  float e = __expf(2.0f * x);
  return 1.0f - 2.0f / (e + 1.0f);
}

// ---------------------------------------------------------------------------
// Prep: transpose+convert weights [512][512] f32 (k-major) -> bf16 [g*512+h][k]
// ---------------------------------------------------------------------------
__global__ __launch_bounds__(256) void prep_wT(
    const float* __restrict__ Wax, const float* __restrict__ Wix,
    const float* __restrict__ Wfx, const float* __restrict__ Wox,
    const float* __restrict__ Wah, const float* __restrict__ Wih,
    const float* __restrict__ Wfh, const float* __restrict__ Woh,
    unsigned short* __restrict__ WxT, unsigned short* __restrict__ WhT) {
  __shared__ float tile[32][33];
  int bx = blockIdx.x;              // 8 mats * 256 tiles
  int mat = bx >> 8;
  int t32 = bx & 255;
  int k0 = (t32 & 15) * 32;
  int h0 = (t32 >> 4) * 32;
  const float* S =
      (mat == 0) ? Wax : (mat == 1) ? Wix : (mat == 2) ? Wfx :
      (mat == 3) ? Wox : (mat == 4) ? Wah : (mat == 5) ? Wih :
      (mat == 6) ? Wfh : Woh;
  unsigned short* D = (mat < 4) ? WxT : WhT;
  int g = mat & 3;
  int tx = threadIdx.x & 31, ty = threadIdx.x >> 5;  // ty in [0,8)
#pragma unroll
  for (int r = 0; r < 4; ++r)
    tile[ty + r * 8][tx] = S[(size_t)(k0 + ty + r * 8) * 512 + h0 + tx];
  __syncthreads();
#pragma unroll
  for (int r = 0; r < 4; ++r) {
    int h = h0 + ty + r * 8;
    int k = k0 + tx;
    D[((size_t)(g * 512 + h) << 9) + k] = f2bf(tile[tx][ty + r * 8]);
  }
}

// X f32 [32768][512] -> bf16
__global__ __launch_bounds__(256) void prep_xbf(const float* __restrict__ X,
                                                unsigned short* __restrict__ Xbf) {
  size_t i = (size_t)blockIdx.x * 256 + threadIdx.x;
  f32x4 v = *(const f32x4*)(X + i * 4);
  short4v o;
  o[0] = (short)f2bf(v[0]); o[1] = (short)f2bf(v[1]);
  o[2] = (short)f2bf(v[2]); o[3] = (short)f2bf(v[3]);
  *(short4v*)(Xbf + i * 4) = o;
}

__global__ __launch_bounds__(256) void prep_bias(
    const float* __restrict__ ba, const float* __restrict__ bi,
    const float* __restrict__ bf, const float* __restrict__ bo,
    float* __restrict__ biascat) {
  int n = blockIdx.x * 256 + threadIdx.x;  // [0,2048)
  int g = n >> 9, h = n & 511;
  const float* s = (g == 0) ? ba : (g == 1) ? bi : (g == 2) ? bf : bo;
  biascat[n] = s[h];
}

// ---------------------------------------------------------------------------
// Phase A: Xg = Xbf @ WxT^T + bias, output layout [t*4+g][h/8][b][h%8] bf16.
// ---------------------------------------------------------------------------
__global__ __launch_bounds__(256) void gemm_xproj(
    const unsigned short* __restrict__ Xbf,   // [32768][512]
    const unsigned short* __restrict__ WxT,   // [2048][512]
    const float* __restrict__ biascat,        // [2048]
    unsigned short* __restrict__ Xg) {        // [2048][64][64][8] bf16
  __shared__ unsigned short Asm[128 * 64];
  __shared__ unsigned short Bsm[128 * 64];
  int bx = blockIdx.x;
  int nt = bx & 15, mt = bx >> 4;
  int m0 = mt * 128, n0 = nt * 128;
  int tid = threadIdx.x;
  int w = tid >> 6, l = tid & 63;
  int wm = (w >> 1) * 64, wn = (w & 1) * 64;
  f32x4 acc[4][4] = {};

  for (int ks = 0; ks < 8; ++ks) {
    int k0 = ks * 64;
    __syncthreads();
    int lr = l >> 3;
    int ksl = ((l & 7) ^ lr) * 8;
#pragma unroll
    for (int ii = 0; ii < 4; ++ii) {
      int i = w * 4 + ii;
      int r = i * 8 + lr;
      gload_lds16(Xbf + (size_t)(m0 + r) * 512 + k0 + ksl, Asm + i * 512 + l * 8);
    }
#pragma unroll
    for (int ii = 0; ii < 4; ++ii) {
      int i = w * 4 + ii;
      int r = i * 8 + lr;
      gload_lds16(WxT + (size_t)(n0 + r) * 512 + k0 + ksl, Bsm + i * 512 + l * 8);
    }
    __syncthreads();
#pragma unroll
    for (int kk = 0; kk < 2; ++kk) {
      short8 af[4], bfr[4];
#pragma unroll
      for (int mi = 0; mi < 4; ++mi) {
        int row = wm + mi * 16 + (l & 15);
        int slot = (kk * 4 + (l >> 4)) ^ (row & 7);
        af[mi] = *(const short8*)(Asm + row * 64 + slot * 8);
      }
#pragma unroll
      for (int ni = 0; ni < 4; ++ni) {
        int row = wn + ni * 16 + (l & 15);
        int slot = (kk * 4 + (l >> 4)) ^ (row & 7);
        bfr[ni] = *(const short8*)(Bsm + row * 64 + slot * 8);
      }
#pragma unroll
      for (int mi = 0; mi < 4; ++mi)
#pragma unroll
        for (int ni = 0; ni < 4; ++ni)
          acc[mi][ni] = __builtin_amdgcn_mfma_f32_16x16x32_bf16(
              af[mi], bfr[ni], acc[mi][ni], 0, 0, 0);
    }
  }
  // epilogue: C/D col=l&15, row=(l>>4)*4+r; write [t4g][chunk][b][e] layout
#pragma unroll
  for (int mi = 0; mi < 4; ++mi)
#pragma unroll
    for (int ni = 0; ni < 4; ++ni) {
      int col = n0 + wn + ni * 16 + (l & 15);
      float bias = biascat[col];
      int g = col >> 9, h = col & 511;
      int chunk = h >> 3, e = h & 7;
#pragma unroll
      for (int r = 0; r < 4; ++r) {
        int m = m0 + wm + mi * 16 + (l >> 4) * 4 + r;
        int t = m >> 6, b = m & 63;
        Xg[(((size_t)(t * 4 + g) * 64 + chunk) * 64 + b) * 8 + e] =
            f2bf(acc[mi][ni][r] + bias);
      }
    }
}

// ---------------------------------------------------------------------------
// Phase B: persistent scan v3. 32 blocks x 4 waves, zero LDS, zero barriers.
// Block j: batch group mi=j&1 (rows mi*32..+31), col chunk cc=j>>1.
// Wave w owns 8 hcols x 4 gates; MFMA operands swapped: A=WhT frag (regs),
// B=h frag -> D col(lane)=batch, rows = gate*8 + lc. Gates fully lane-local.
// hbuf: [parity][chunk=hcol/8][b][8] bf16, sc0sc1 stores/loads (L3-coherent).
// Flags: 1 per producer wave (128B stride), relaxed agent atomics.
// ---------------------------------------------------------------------------
__global__ __launch_bounds__(256, 1) void lstm_scan(
    const unsigned short* __restrict__ Xg,   // [2048][64][64][8] bf16
    const unsigned short* __restrict__ WhT,  // [2048][512] bf16
    unsigned short* __restrict__ hbuf,       // [2][64][64][8] bf16 (no init)
    int* __restrict__ flags,                 // [128*32] ints, zeroed
    float* __restrict__ out) {               // [512][64][512] f32
  const int j = blockIdx.x;   // 0..31
  const int mi = j & 1;
  const int cc = j >> 1;
  const int tid = threadIdx.x;
  const int w = tid >> 6, l = tid & 63;

  // ---- recurrent weights as A-fragments, resident all 512 steps ----
  // A row m=l&31 -> gate g=m>>3, local col lc=m&7; k=(l>>5)*8+i, step 16/kt
  short8 wf[32];
  {
    const int m = l & 31;
    const int g = m >> 3;
    const int hcol_w = cc * 32 + w * 8 + (m & 7);
    const unsigned short* base =
        WhT + (((size_t)(g * 512 + hcol_w)) << 9) + (l >> 5) * 8;
#pragma unroll
    for (int kt = 0; kt < 32; ++kt) wf[kt] = *(const short8*)(base + kt * 16);
  }

  const int b = mi * 32 + (l & 31);          // this lane's batch row
  const int hcol0 = cc * 32 + w * 8 + (l >> 5) * 4;  // first of 4 hcols
  const int mychunk = cc * 4 + w;

  // B-frag load voffset (bytes): chunk=(kt*2+(l>>5)), row b
  const unsigned ld_voff0 = (unsigned)((l >> 5) * 1024 + b * 16);
  // h store voffset (bytes): chunk=mychunk, row b, half (l>>5)
  const unsigned st_voff = (unsigned)(mychunk * 1024 + b * 16 + (l >> 5) * 8);

  int* const myflag = flags + (mi * 64 + mychunk) * 32;
  int* const pollflag = flags + (mi * 64 + l) * 32;

  float s4[4] = {0.f, 0.f, 0.f, 0.f};  // cell state, registers, all steps

  // prefetch Xg for t=0
  uint2 xgn[4];
#pragma unroll
  for (int g = 0; g < 4; ++g)
    xgn[g] = *(const uint2*)(Xg +
        ((((size_t)(0 * 4 + g) * 64 + mychunk) * 64 + b) * 8 + (l >> 5) * 4));

#pragma unroll 1
  for (int t = 0; t < TSTEPS; ++t) {
    f32x16 asum = {};
    if (t > 0) {
      // ---- wait for all 64 producer waves of this batch group ----
      int fv;
      do {
        fv = __hip_atomic_load(pollflag, __ATOMIC_RELAXED,
                               __HIP_MEMORY_SCOPE_AGENT);
      } while (!__all(fv >= t));
      asm volatile("" ::: "memory");
      // ---- load 32 B-fragments (coalesced dwordx4, L2-bypass) ----
      const unsigned short* hbase = hbuf + (size_t)((t - 1) & 1) * 32768;
      short8 bfrag[32];
#pragma unroll
      for (int kt = 0; kt < 32; ++kt) {
        asm volatile("global_load_dwordx4 %0, %1, %2 sc0 sc1"
                     : "=v"(bfrag[kt])
                     : "v"(ld_voff0 + (unsigned)(kt * 2048)), "s"(hbase));
      }
      asm volatile("s_waitcnt vmcnt(0)" ::: "memory");
      __builtin_amdgcn_sched_barrier(0);
      // ---- 32 MFMAs, 2 interleaved accumulators ----
      f32x16 a0 = {}, a1 = {};
#pragma unroll
      for (int kt = 0; kt < 32; kt += 2) {
        a0 = __builtin_amdgcn_mfma_f32_32x32x16_bf16(wf[kt], bfrag[kt], a0,
                                                     0, 0, 0);
        a1 = __builtin_amdgcn_mfma_f32_32x32x16_bf16(wf[kt + 1], bfrag[kt + 1],
                                                     a1, 0, 0, 0);
      }
      asum = a0 + a1;
    }
    // ---- gates: acc[r]: gate g=r>>2, q=r&3 (cols hcol0+q), batch b ----
    float hout[4];
#pragma unroll
    for (int q = 0; q < 4; ++q) {
      float pa = asum[0 * 4 + q] + bf2f((unsigned short)((q < 2 ? xgn[0].x : xgn[0].y) >> ((q & 1) * 16)));
      float pi = asum[1 * 4 + q] + bf2f((unsigned short)((q < 2 ? xgn[1].x : xgn[1].y) >> ((q & 1) * 16)));
      float pf = asum[2 * 4 + q] + bf2f((unsigned short)((q < 2 ? xgn[2].x : xgn[2].y) >> ((q & 1) * 16)));
      float po = asum[3 * 4 + q] + bf2f((unsigned short)((q < 2 ? xgn[3].x : xgn[3].y) >> ((q & 1) * 16)));
      float a  = tanh_fast(pa);
      float ig = sigmoid_fast(pi);
      float fg = sigmoid_fast(pf);
      float og = sigmoid_fast(po);
      s4[q] = a * ig + s4[q] * fg;
      hout[q] = tanh_fast(s4[q]) * og;
    }
    // ---- publish h(t): coalesced 8B sc0sc1 store, vmcnt drain, flag ----
    {
      unsigned lo = (unsigned)f2bf(hout[0]) | ((unsigned)f2bf(hout[1]) << 16);
      unsigned hi = (unsigned)f2bf(hout[2]) | ((unsigned)f2bf(hout[3]) << 16);
      uint2 hd; hd.x = lo; hd.y = hi;
      const unsigned short* sbase = hbuf + (size_t)(t & 1) * 32768;
      asm volatile("global_store_dwordx2 %0, %1, %2 sc0 sc1"
                   :: "v"(st_voff), "v"(hd), "s"(sbase) : "memory");
      asm volatile("s_waitcnt vmcnt(0)" ::: "memory");
      if (l == 0)
        __hip_atomic_store(myflag, t + 1, __ATOMIC_RELAXED,
                           __HIP_MEMORY_SCOPE_AGENT);
    }
    // ---- off critical path: out store + next Xg prefetch ----
    f32x4 ov;
    ov[0] = hout[0]; ov[1] = hout[1]; ov[2] = hout[2]; ov[3] = hout[3];
    *(f32x4*)(out + ((size_t)t * 64 + b) * 512 + hcol0) = ov;
    const int tn = (t + 1 < TSTEPS) ? t + 1 : t;
#pragma unroll
    for (int g = 0; g < 4; ++g)
      xgn[g] = *(const uint2*)(Xg +
          ((((size_t)(tn * 4 + g) * 64 + mychunk) * 64 + b) * 8 + (l >> 5) * 4));
  }
}

// ---------------------------------------------------------------------------
// Workspace layout (bytes):
//   0          Xg bf16     134217728
//   134217728  Xbf bf16     33554432  (dead after gemm_xproj)
//   134217728  hbuf bf16      262144  (overlaps Xbf; no init needed)
//   167772160  WxT bf16      2097152
//   169869312  WhT bf16      2097152
//   171966464  biascat f32      8192
//   171974656  flags           16384  (zeroed)
// ---------------------------------------------------------------------------
extern "C" void kernel_launch(void* const* d_in, const int* in_sizes, int n_in,
                              void* d_out, int out_size, void* d_ws,
                              size_t ws_size, hipStream_t stream) {
  const float* X   = (const float*)d_in[0];
  const float* Wax = (const float*)d_in[1];
  const float* Wix = (const float*)d_in[2];
  const float* Wfx = (const float*)d_in[3];
  const float* Wox = (const float*)d_in[4];
  const float* Wah = (const float*)d_in[5];
  const float* Wih = (const float*)d_in[6];
  const float* Wfh = (const float*)d_in[7];
  const float* Woh = (const float*)d_in[8];
  const float* ba  = (const float*)d_in[9];
  const float* bi  = (const float*)d_in[10];
  const float* bf  = (const float*)d_in[11];
  const float* bo  = (const float*)d_in[12];

  char* ws = (char*)d_ws;
  unsigned short* Xg   = (unsigned short*)(ws);
  unsigned short* Xbf  = (unsigned short*)(ws + 134217728);
  unsigned short* hbuf = (unsigned short*)(ws + 134217728);  // reuses Xbf
  unsigned short* WxT  = (unsigned short*)(ws + 167772160);
  unsigned short* WhT  = (unsigned short*)(ws + 169869312);
  float*          bcat = (float*)(ws + 171966464);
  int*            flags= (int*)(ws + 171974656);

  hipMemsetAsync(ws + 171974656, 0, 16384, stream);  // flags = 0

  prep_wT<<<2048, 256, 0, stream>>>(Wax, Wix, Wfx, Wox, Wah, Wih, Wfh, Woh,
                                    WxT, WhT);
  prep_xbf<<<16384, 256, 0, stream>>>(X, Xbf);
  prep_bias<<<8, 256, 0, stream>>>(ba, bi, bf, bo, bcat);
  gemm_xproj<<<4096, 256, 0, stream>>>(Xbf, WxT, bcat, Xg);
  lstm_scan<<<32, 256, 0, stream>>>(Xg, WhT, hbuf, flags, (float*)d_out);
}